// Round 14
// baseline (140.282 us; speedup 1.0000x reference)
//
#include <hip/hip_runtime.h>
#include <cstdint>
#include <cstddef>

#define THETA 1.2f
#define XI 0.3f
#define BDIM 8192
#define DDIM 512
#define NWORK 288          // jg8-major: sum_{jg8=0..7} (8*jg8+8)
#define NPAIRS_UP (((double)BDIM * (double)(BDIM + 1)) * 0.5)

typedef float f32x4 __attribute__((ext_vector_type(4)));
typedef int i32x8 __attribute__((ext_vector_type(8)));

// Kernel 1: per-row L2 normalize fp32 -> fp8 e4m3, coalesced; sq[row]=||n||^2; zero counter.
__global__ __launch_bounds__(256) void normalize_rows(
    const float* __restrict__ x, unsigned char* __restrict__ nf8,
    float* __restrict__ sq, unsigned int* __restrict__ counter)
{
    if (blockIdx.x == 0 && threadIdx.x == 0) { *counter = 0u; }
    int row = blockIdx.x * 4 + (threadIdx.x >> 6);
    int l = threadIdx.x & 63;
    const float4* xr = (const float4*)(x + (size_t)row * DDIM);
    float4 f0 = xr[l];
    float4 f1 = xr[l + 64];
    float s = f0.x*f0.x + f0.y*f0.y + f0.z*f0.z + f0.w*f0.w
            + f1.x*f1.x + f1.y*f1.y + f1.z*f1.z + f1.w*f1.w;
    #pragma unroll
    for (int m = 1; m < 64; m <<= 1) s += __shfl_xor(s, m);
    float rn = rsqrtf(s);
    int pk0 = __builtin_amdgcn_cvt_pk_fp8_f32(f0.x * rn, f0.y * rn, 0, false);
    pk0     = __builtin_amdgcn_cvt_pk_fp8_f32(f0.z * rn, f0.w * rn, pk0, true);
    int pk1 = __builtin_amdgcn_cvt_pk_fp8_f32(f1.x * rn, f1.y * rn, 0, false);
    pk1     = __builtin_amdgcn_cvt_pk_fp8_f32(f1.z * rn, f1.w * rn, pk1, true);
    int* rowp = (int*)(nf8 + (size_t)row * DDIM);
    rowp[l] = pk0;
    rowp[l + 64] = pk1;
    if (l == 0) sq[row] = s * rn * rn;
}

// Kernel 2: 288 jg8-major blocks, 512 threads (8 waves). Block = 128-row A-panel
// (64 KB LDS, staged once) x 1024-col j-group: 8 j-tiles = 32 subtiles of 64x64;
// each wave computes 4 subtiles (s = w + pass*8). mfma_scale 16x16x128 fp8,
// B single-buffered direct from L2-hot global. Fused hinge, analytic XI, ticket finalize.
__global__ __launch_bounds__(512) void gram_hinge(
    const unsigned char* __restrict__ nf8, const float* __restrict__ sq,
    const int* __restrict__ y, double* __restrict__ part,
    unsigned int* __restrict__ counter, float* __restrict__ out)
{
    // jg8-major decode, reversed (big j-groups first; partial diagonal blocks last)
    // u in [4*jg8*(jg8+1), 4*(jg8+1)*(jg8+2)) -> bi = u - 4*jg8*(jg8+1), bi in 0..8*jg8+7
    int u = (NWORK - 1) - (int)blockIdx.x;
    int jg = (int)((sqrtf(1.0f + (float)u) - 1.0f) * 0.5f);
    while (4 * (jg + 1) * (jg + 2) <= u) ++jg;
    while (4 * jg * (jg + 1) > u) --jg;
    int bi = u - 4 * jg * (jg + 1);

    __shared__ unsigned char As[128 * 512];   // 64 KB A-panel, granule-swizzled rows
    __shared__ float sqA[128];
    __shared__ int   yA[128];
    __shared__ float sqB[1024];
    __shared__ int   yB[1024];
    __shared__ float wpart[8];
    __shared__ double dpart[8];
    __shared__ int is_last;

    int tid = threadIdx.x;
    int w = tid >> 6, l = tid & 63;     // 8 waves
    int lr = l & 15, q = l >> 4;

    // ---- stage A-panel once: 8 DMA instrs/wave, 1 KB contiguous (2 rows) each ----
    const unsigned char* gA = nf8 + (size_t)bi * 128 * DDIM;
    {
        int rl = l >> 5;
        int gl = l & 31;
        #pragma unroll
        for (int i = 0; i < 8; ++i) {
            int rbase = w * 16 + i * 2;
            int r = rbase + rl;
            int gg = gl ^ (r & 7);   // in-row 16-B granule swizzle (coalescing-safe)
            __builtin_amdgcn_global_load_lds(
                (const __attribute__((address_space(1))) void*)(gA + (size_t)r * DDIM + gg * 16),
                (__attribute__((address_space(3))) void*)(As + rbase * 512), 16, 0, 0);
        }
    }
    // ---- stage sq/y: A-rows (128) + this jg's 1024 cols ----
    {
        int arow = bi * 128;
        if (tid < 128) { sqA[tid] = sq[arow + tid]; yA[tid] = y[arow + tid]; }
        int cb = jg * 1024;
        sqB[tid]       = sq[cb + tid];
        sqB[tid + 512] = sq[cb + tid + 512];
        yB[tid]        = y[cb + tid];
        yB[tid + 512]  = y[cb + tid + 512];
    }
    __syncthreads();   // single drain+barrier per block

    float acc0 = 0.f, acc1 = 0.f, acc2 = 0.f, acc3 = 0.f;

    #pragma unroll 1   // one pass's accv live at a time (register budget)
    for (int pass = 0; pass < 4; ++pass) {
        int s = w + pass * 8;            // subtile 0..31
        int jt = s >> 2;                 // j-tile 0..7
        int quad = s & 3;
        int wr = quad >> 1, wc = quad & 1;
        int bj = jg * 8 + jt;
        if (bj < bi) continue;           // j-tile below diagonal (wave-uniform)

        f32x4 accv[4][4] = {};
        const unsigned char* rowB =
            nf8 + ((size_t)(bj * 128 + wc * 64 + lr)) * DDIM + q * 32;

        #pragma unroll
        for (int it = 0; it < 4; ++it) {
            int k0 = it * 128;
            i32x8 bfr[4];
            #pragma unroll
            for (int ni = 0; ni < 4; ++ni) {
                const int4* bp = (const int4*)(rowB + (size_t)ni * 16 * DDIM + k0);
                int4 b0 = bp[0], b1 = bp[1];
                bfr[ni][0] = b0.x; bfr[ni][1] = b0.y; bfr[ni][2] = b0.z; bfr[ni][3] = b0.w;
                bfr[ni][4] = b1.x; bfr[ni][5] = b1.y; bfr[ni][6] = b1.z; bfr[ni][7] = b1.w;
            }
            #pragma unroll
            for (int mi = 0; mi < 4; ++mi) {
                int r = wr * 64 + mi * 16 + lr;
                int G0 = it * 8 + q * 2;
                int sw = r & 7;
                int4 a0 = *(const int4*)(As + r * 512 + ((G0 ^ sw) << 4));
                int4 a1 = *(const int4*)(As + r * 512 + (((G0 | 1) ^ sw) << 4));
                i32x8 af;
                af[0] = a0.x; af[1] = a0.y; af[2] = a0.z; af[3] = a0.w;
                af[4] = a1.x; af[5] = a1.y; af[6] = a1.z; af[7] = a1.w;
                #pragma unroll
                for (int ni = 0; ni < 4; ++ni)
                    accv[mi][ni] = __builtin_amdgcn_mfma_scale_f32_16x16x128_f8f6f4(
                        af, bfr[ni], accv[mi][ni],
                        0, 0, 0, 0x7F7F7F7F, 0, 0x7F7F7F7F);
            }
        }

        // ---- Epilogue (C/D: col=lane&15 (j), row=q*4+reg (i)) ----
        int jrow = jt * 128 + wc * 64 + lr;   // index into sqB/yB
        float sqj[4]; int yj[4];
        #pragma unroll
        for (int ni = 0; ni < 4; ++ni) {
            sqj[ni] = sqB[jrow + ni * 16];
            yj[ni]  = yB[jrow + ni * 16];
        }
        if (bj != bi) {
            #pragma unroll
            for (int mi = 0; mi < 4; ++mi) {
                #pragma unroll
                for (int r = 0; r < 4; ++r) {
                    int ia = wr * 64 + mi * 16 + q * 4 + r;
                    float ci = THETA - sqA[ia];
                    int yi = yA[ia];
                    float h0 = fmaxf(fmaf(2.f, accv[mi][0][r], ci - sqj[0]), 0.f);
                    acc0 += (yi == yj[0]) ? h0 : -h0;
                    float h1 = fmaxf(fmaf(2.f, accv[mi][1][r], ci - sqj[1]), 0.f);
                    acc1 += (yi == yj[1]) ? h1 : -h1;
                    float h2 = fmaxf(fmaf(2.f, accv[mi][2][r], ci - sqj[2]), 0.f);
                    acc2 += (yi == yj[2]) ? h2 : -h2;
                    float h3 = fmaxf(fmaf(2.f, accv[mi][3][r], ci - sqj[3]), 0.f);
                    acc3 += (yi == yj[3]) ? h3 : -h3;
                }
            }
        } else {
            // diagonal j-tile: local col (wc*64+lr+ni*16) >= local row
            #pragma unroll
            for (int mi = 0; mi < 4; ++mi) {
                #pragma unroll
                for (int r = 0; r < 4; ++r) {
                    int rl_ = wr * 64 + mi * 16 + q * 4 + r;
                    float ci = THETA - sqA[rl_];
                    int yi = yA[rl_];
                    #pragma unroll
                    for (int ni = 0; ni < 4; ++ni) {
                        int cl = wc * 64 + lr + ni * 16;
                        float h = fmaxf(fmaf(2.f, accv[mi][ni][r], ci - sqj[ni]), 0.f);
                        float sh = (yi == yj[ni]) ? h : -h;
                        if (cl >= rl_) acc0 += sh;
                    }
                }
            }
        }
    }

    float local = (acc0 + acc1) + (acc2 + acc3);
    #pragma unroll
    for (int off = 32; off > 0; off >>= 1) local += __shfl_down(local, off);
    if (l == 0) wpart[w] = local;
    __syncthreads();
    if (tid == 0) {
        double ssum = 0.0;
        #pragma unroll
        for (int i = 0; i < 8; ++i) ssum += (double)wpart[i];
        __hip_atomic_store(&part[blockIdx.x], ssum, __ATOMIC_RELEASE, __HIP_MEMORY_SCOPE_AGENT);
        unsigned int ticket = __hip_atomic_fetch_add(
            counter, 1u, __ATOMIC_ACQ_REL, __HIP_MEMORY_SCOPE_AGENT);
        is_last = (ticket == NWORK - 1) ? 1 : 0;
    }
    __syncthreads();
    if (is_last) {
        double s = 0.0;
        for (int i = tid; i < NWORK; i += 512)
            s += __hip_atomic_load(&part[i], __ATOMIC_ACQUIRE, __HIP_MEMORY_SCOPE_AGENT);
        #pragma unroll
        for (int off = 32; off > 0; off >>= 1) s += __shfl_down(s, off);
        if (l == 0) dpart[w] = s;
        __syncthreads();
        if (tid == 0) {
            double total = 0.0;
            #pragma unroll
            for (int i = 0; i < 8; ++i) total += dpart[i];
            total += (double)XI * NPAIRS_UP;
            const double m = 1.0 / ((double)BDIM * (double)BDIM - (double)BDIM);
            out[0] = (float)(total * m);
        }
    }
}

extern "C" void kernel_launch(void* const* d_in, const int* in_sizes, int n_in,
                              void* d_out, int out_size, void* d_ws, size_t ws_size,
                              hipStream_t stream) {
    const float* x = (const float*)d_in[0];
    const int* y = (const int*)d_in[1];
    float* out = (float*)d_out;

    unsigned char* nf8 = (unsigned char*)d_ws;                          // 4 MB fp8
    char* p = (char*)d_ws + (size_t)BDIM * DDIM;
    float* sq = (float*)p;                                              // 32 KB
    unsigned int* counter = (unsigned int*)(p + (size_t)BDIM * 4);
    double* part = (double*)(p + (size_t)BDIM * 4 + 64);                // NWORK doubles

    normalize_rows<<<BDIM / 4, 256, 0, stream>>>(x, nf8, sq, counter);
    gram_hinge<<<NWORK, 512, 0, stream>>>(nf8, sq, y, part, counter, out);
}